// Round 1
// baseline (3504.569 us; speedup 1.0000x reference)
//
#include <hip/hip_runtime.h>

// SwitchGNN: out = (1/T) * sum_t [ (segsum_t(x[src])/max(cnt,1)) @ W_t + 1{cnt>0} b_t ]
// Phase 1: scatter-add x rows into per-(type,node) accumulator agg + counts.
// Phase 2: per-type GEMM agg@W with per-node scaling, accumulated into out.

constexpr int NN = 100000;   // nodes
constexpr int NT = 7;        // edge types
constexpr int NE = 250000;   // edges per type
constexpr int DD = 128;      // feature dim

// ---------------------------------------------------------------- scatter ---
// 32 threads per edge; each thread gathers float4 of x[src] and atomicAdds
// into agg[t][dst]. Lane 0 bumps the count.
__global__ __launch_bounds__(256) void scatter_k(
    const float* __restrict__ x,
    const int* __restrict__ ei,      // [tc][2][NE], offset to chunk base
    float* __restrict__ agg,         // [tc][NN][DD]
    float* __restrict__ cnt,         // [tc][NN]
    int nedge_total)                 // tc*NE
{
    int gid = blockIdx.x * 256 + threadIdx.x;
    int lane = gid & 31;
    int ge = gid >> 5;
    if (ge >= nedge_total) return;
    int t = ge / NE;
    int e = ge - t * NE;
    const int* eit = ei + (size_t)t * 2 * NE;
    int src = eit[e];
    int dst = eit[NE + e];
    const float4 v = *reinterpret_cast<const float4*>(x + (size_t)src * DD + lane * 4);
    float* arow = agg + ((size_t)t * NN + dst) * DD + lane * 4;
    atomicAdd(arow + 0, v.x);
    atomicAdd(arow + 1, v.y);
    atomicAdd(arow + 2, v.z);
    atomicAdd(arow + 3, v.w);
    if (lane == 0) atomicAdd(cnt + (size_t)t * NN + dst, 1.0f);
}

// ------------------------------------------------------------------ gemm ----
// Block: 256 threads = 16(tx: 8 outputs each) x 16(ty: 4 nodes each).
// Tile: 64 nodes x 128 outputs, K chunked by 64. LDS ~49.6KB -> 3 blocks/CU.
constexpr int TN = 64;   // node tile
constexpr int DC = 64;   // d (reduction) chunk
constexpr int PAD = 5;   // sA row pad: stride 69 -> 4 ty-groups hit distinct banks

__global__ __launch_bounds__(256) void gemm_k(
    const float* __restrict__ agg,   // [tc][NN][DD]
    const float* __restrict__ cnt,   // [tc][NN]
    const float* __restrict__ Wt,    // W + t0*DD*DD
    const float* __restrict__ bt,    // b + t0*DD
    float* __restrict__ out,         // [NN][DD], accumulated (+=)
    int tc)
{
    __shared__ float sW[DC][DD];        // 32 KB
    __shared__ float sA[TN][DC + PAD];  // 17.6 KB

    const int tid = threadIdx.x;
    const int tx = tid & 15;    // output block: f0 = tx*8
    const int ty = tid >> 4;    // node block:  n = n0 + ty*4 + i
    const int n0 = blockIdx.x * TN;
    const float inv7 = 1.0f / (float)NT;

    float accT[4][8];
    #pragma unroll
    for (int i = 0; i < 4; ++i)
        #pragma unroll
        for (int j = 0; j < 8; ++j) accT[i][j] = 0.0f;

    for (int t = 0; t < tc; ++t) {
        float acc[4][8];
        #pragma unroll
        for (int i = 0; i < 4; ++i)
            #pragma unroll
            for (int j = 0; j < 8; ++j) acc[i][j] = 0.0f;

        for (int d0 = 0; d0 < DD; d0 += DC) {
            __syncthreads();   // protect sW/sA from previous chunk's readers
            // stage W[t][d0..d0+63][0..127]: 2048 float4 / 256 threads = 8 each
            const float4* wsrc =
                reinterpret_cast<const float4*>(Wt + ((size_t)t * DD + d0) * DD);
            #pragma unroll
            for (int k = 0; k < 8; ++k) {
                int idx = tid + k * 256;              // float4 index
                reinterpret_cast<float4*>(&sW[idx >> 5][0])[idx & 31] = wsrc[idx];
            }
            // stage agg[t][n0..n0+63][d0..d0+63]: 1024 float4 / 256 = 4 each
            const float* asrc = agg + (size_t)t * NN * DD + d0;
            #pragma unroll
            for (int k = 0; k < 4; ++k) {
                int idx = tid + k * 256;              // float4 idx in 64x16 grid
                int r = idx >> 4, c4 = idx & 15;
                float4 v = make_float4(0.f, 0.f, 0.f, 0.f);
                int n = n0 + r;
                if (n < NN)
                    v = reinterpret_cast<const float4*>(asrc + (size_t)n * DD)[c4];
                sA[r][c4 * 4 + 0] = v.x;
                sA[r][c4 * 4 + 1] = v.y;
                sA[r][c4 * 4 + 2] = v.z;
                sA[r][c4 * 4 + 3] = v.w;
            }
            __syncthreads();

            #pragma unroll 8
            for (int d = 0; d < DC; ++d) {
                float a[4];
                #pragma unroll
                for (int i = 0; i < 4; ++i) a[i] = sA[ty * 4 + i][d];
                float4 w0 = *reinterpret_cast<const float4*>(&sW[d][tx * 8]);
                float4 w1 = *reinterpret_cast<const float4*>(&sW[d][tx * 8 + 4]);
                float w[8] = {w0.x, w0.y, w0.z, w0.w, w1.x, w1.y, w1.z, w1.w};
                #pragma unroll
                for (int i = 0; i < 4; ++i)
                    #pragma unroll
                    for (int j = 0; j < 8; ++j)
                        acc[i][j] = fmaf(a[i], w[j], acc[i][j]);
            }
        }

        // fold this type into the cross-type accumulator with per-node scale
        float bv[8];
        #pragma unroll
        for (int j = 0; j < 8; ++j) bv[j] = bt[(size_t)t * DD + tx * 8 + j];
        #pragma unroll
        for (int i = 0; i < 4; ++i) {
            int n = n0 + ty * 4 + i;
            if (n < NN) {
                float c = cnt[(size_t)t * NN + n];
                float s = 1.0f / fmaxf(c, 1.0f);
                float hb = (c > 0.0f) ? 1.0f : 0.0f;
                #pragma unroll
                for (int j = 0; j < 8; ++j)
                    accT[i][j] += s * acc[i][j] + hb * bv[j];
            }
        }
    }

    // out += (1/7) * accT   (out zero-initialized; chunks accumulate serially)
    #pragma unroll
    for (int i = 0; i < 4; ++i) {
        int n = n0 + ty * 4 + i;
        if (n >= NN) continue;
        float* orow = out + (size_t)n * DD + tx * 8;
        float4 o0 = *reinterpret_cast<float4*>(orow);
        float4 o1 = *reinterpret_cast<float4*>(orow + 4);
        o0.x += inv7 * accT[i][0];
        o0.y += inv7 * accT[i][1];
        o0.z += inv7 * accT[i][2];
        o0.w += inv7 * accT[i][3];
        o1.x += inv7 * accT[i][4];
        o1.y += inv7 * accT[i][5];
        o1.z += inv7 * accT[i][6];
        o1.w += inv7 * accT[i][7];
        *reinterpret_cast<float4*>(orow) = o0;
        *reinterpret_cast<float4*>(orow + 4) = o1;
    }
}

// ---------------------------------------------------------------- launch ----
extern "C" void kernel_launch(void* const* d_in, const int* in_sizes, int n_in,
                              void* d_out, int out_size, void* d_ws, size_t ws_size,
                              hipStream_t stream) {
    const float* x  = (const float*)d_in[0];
    const int*   ei = (const int*)d_in[1];    // [NT][2][NE] int32
    const float* W  = (const float*)d_in[2];  // [NT][DD][DD]
    const float* b  = (const float*)d_in[3];  // [NT][DD]
    float* out = (float*)d_out;

    const size_t perTypeFloats = (size_t)NN * DD + NN;       // agg row + cnt
    const size_t perTypeBytes  = perTypeFloats * sizeof(float);
    int tcmax = (int)(ws_size / perTypeBytes);
    if (tcmax < 1) tcmax = 1;                 // require >= 52MB workspace
    if (tcmax > NT) tcmax = NT;

    hipMemsetAsync(d_out, 0, (size_t)NN * DD * sizeof(float), stream);

    for (int t0 = 0; t0 < NT; t0 += tcmax) {
        int tc = (NT - t0 < tcmax) ? (NT - t0) : tcmax;
        float* agg = (float*)d_ws;
        float* cnt = agg + (size_t)tc * NN * DD;
        hipMemsetAsync(d_ws, 0, (size_t)tc * perTypeBytes, stream);

        int nedges = tc * NE;
        scatter_k<<<nedges / 8, 256, 0, stream>>>(
            x, ei + (size_t)t0 * 2 * NE, agg, cnt, nedges);

        gemm_k<<<(NN + TN - 1) / TN, 256, 0, stream>>>(
            agg, cnt, W + (size_t)t0 * DD * DD, b + (size_t)t0 * DD, out, tc);
    }
}

// Round 2
// 542.716 us; speedup vs baseline: 6.4575x; 6.4575x over previous
//
#include <hip/hip_runtime.h>

// SwitchGNN restructured:
//  out = (1/7) * sum_t [ (segsum_t(x[src]) / max(cnt,1)) @ W_t + 1{cnt>0} b_t ]
// P1 fill_k : bucket edges by (t,dst)   (1 int atomic/edge, cap 32)
// P2 agg_k  : gather-sum x rows per (t,n), scale 1/cnt, emit bf16 pre-swizzled
// P3 wconv_k: W -> bf16, transposed [t][f][k], same XOR swizzle (once)
// P4 gemm_k : 64-row blocks, LDS-staged A/W via global_load_lds(16B),
//             mfma_f32_16x16x32_bf16, bias+mean epilogue, out written once.

constexpr int NN = 100000;
constexpr int NT = 7;
constexpr int NE = 250000;
constexpr int DD = 128;
constexpr int CAP = 32;                 // bucket capacity (P(ovfl)~1e-22 @ lambda=2.5)
constexpr int NTILE = (NN + 63) / 64;   // 1563 GEMM row-tiles

typedef short bf16x8 __attribute__((ext_vector_type(8)));
typedef float f32x4 __attribute__((ext_vector_type(4)));

__device__ __forceinline__ unsigned pack_bf16x2(float lo, float hi) {
    unsigned a = __float_as_uint(lo), b = __float_as_uint(hi);
    unsigned al = (a + 0x7FFFu + ((a >> 16) & 1u)) >> 16;          // RNE
    unsigned bh = (b + 0x7FFFu + ((b >> 16) & 1u)) & 0xFFFF0000u;
    return al | bh;
}

// ------------------------------------------------------------------ fill ----
__global__ __launch_bounds__(256) void fill_k(
    const int* __restrict__ ei,     // [tc][2][NE] (chunk base)
    int* __restrict__ cnt,          // [tc*NN], zeroed
    int* __restrict__ eidx,         // [tc*NN][CAP]
    int nedge)
{
    int id = blockIdx.x * 256 + threadIdx.x;
    if (id >= nedge) return;
    int t = id / NE, e = id - t * NE;
    const int* p = ei + (size_t)t * 2 * NE;
    int src = p[e], dst = p[NE + e];
    int slot = t * NN + dst;
    int pos = atomicAdd(cnt + slot, 1);
    if (pos < CAP) eidx[(size_t)slot * CAP + pos] = src;
}

// ------------------------------------------------------------- aggregate ----
// one wave per (t,n); lane holds k=2*lane, 2*lane+1
__global__ __launch_bounds__(256) void agg_k(
    const float* __restrict__ x,
    const int* __restrict__ cnt,
    const int* __restrict__ eidx,
    char* __restrict__ aggb,        // [tc][NTILE][64 rows][256B], swizzled
    int npair)
{
    int wid = (blockIdx.x * 256 + threadIdx.x) >> 6;
    int lane = threadIdx.x & 63;
    if (wid >= npair) return;
    int t = wid / NN, n = wid - t * NN;
    int c = cnt[wid];
    int cc = c < CAP ? c : CAP;
    const int* bkt = eidx + (size_t)wid * CAP;
    int my = (lane < cc) ? bkt[lane] : 0;   // vectorized index prefetch

    float a0 = 0.f, a1 = 0.f;
    int e = 0;
    for (; e + 4 <= cc; e += 4) {           // 4 independent gathers in flight
        int s0 = __shfl(my, e), s1 = __shfl(my, e + 1);
        int s2 = __shfl(my, e + 2), s3 = __shfl(my, e + 3);
        float2 v0 = *(const float2*)(x + (size_t)s0 * DD + 2 * lane);
        float2 v1 = *(const float2*)(x + (size_t)s1 * DD + 2 * lane);
        float2 v2 = *(const float2*)(x + (size_t)s2 * DD + 2 * lane);
        float2 v3 = *(const float2*)(x + (size_t)s3 * DD + 2 * lane);
        a0 += v0.x + v1.x + v2.x + v3.x;
        a1 += v0.y + v1.y + v2.y + v3.y;
    }
    for (; e < cc; ++e) {
        int s = __shfl(my, e);
        float2 v = *(const float2*)(x + (size_t)s * DD + 2 * lane);
        a0 += v.x; a1 += v.y;
    }
    float s = 1.0f / fmaxf((float)c, 1.0f);  // fold mean-scale pre-GEMM (linear)
    int g = n >> 6, r = n & 63;
    int gran = (lane >> 2) ^ (r & 7);        // XOR swizzle: conflict-free ds_read_b128
    *(unsigned*)(aggb + ((size_t)t * NTILE + g) * 16384 + r * 256 + gran * 16 + (lane & 3) * 4)
        = pack_bf16x2(a0 * s, a1 * s);
}

// ---------------------------------------------------------------- W conv ----
// WTb[t][f][k] bf16, row=256B, granule ^= f&7. One wave per (t,f).
__global__ __launch_bounds__(256) void wconv_k(
    const float* __restrict__ W, char* __restrict__ WTb)
{
    int wid = (blockIdx.x * 256 + threadIdx.x) >> 6;
    int lane = threadIdx.x & 63;
    int t = wid >> 7, f = wid & 127;
    if (t >= NT) return;
    const float* Wt = W + (size_t)t * DD * DD;
    float w0 = Wt[(size_t)(2 * lane) * DD + f];
    float w1 = Wt[(size_t)(2 * lane + 1) * DD + f];
    int gran = (lane >> 2) ^ (f & 7);
    *(unsigned*)(WTb + (size_t)t * 32768 + f * 256 + gran * 16 + (lane & 3) * 4)
        = pack_bf16x2(w0, w1);
}

// ------------------------------------------------------------------ gemm ----
// 4 waves: wave(wy,wx) computes rows wy*32..+31, cols wx*64..+63.
__global__ __launch_bounds__(256) void gemm_k(
    const char* __restrict__ aggb, const char* __restrict__ WTb,
    const int* __restrict__ cnt, const float* __restrict__ bias,
    float* __restrict__ out, int tc, int t0, int accum)
{
    __shared__ char sA[64 * 256];    // 16 KB
    __shared__ char sW[128 * 256];   // 32 KB
    int tid = threadIdx.x;
    int w = tid >> 6, lane = tid & 63;
    int wy = w >> 1, wx = w & 1;
    int n0 = blockIdx.x * 64;

    f32x4 acc[2][4];
    #pragma unroll
    for (int i = 0; i < 2; ++i)
        #pragma unroll
        for (int j = 0; j < 4; ++j) acc[i][j] = (f32x4)0.0f;

    for (int t = 0; t < tc; ++t) {
        __syncthreads();   // prev iter's readers done before restage
        const char* asrc = aggb + ((size_t)t * NTILE + blockIdx.x) * 16384;
        #pragma unroll
        for (int i = 0; i < 4; ++i) {
            int ch = w * 4 + i;
            __builtin_amdgcn_global_load_lds(
                (const __attribute__((address_space(1))) void*)(asrc + ch * 1024 + lane * 16),
                (__attribute__((address_space(3))) void*)(sA + ch * 1024), 16, 0, 0);
        }
        const char* wsrc = WTb + (size_t)(t0 + t) * 32768;
        #pragma unroll
        for (int i = 0; i < 8; ++i) {
            int ch = w * 8 + i;
            __builtin_amdgcn_global_load_lds(
                (const __attribute__((address_space(1))) void*)(wsrc + ch * 1024 + lane * 16),
                (__attribute__((address_space(3))) void*)(sW + ch * 1024), 16, 0, 0);
        }
        __syncthreads();   // compiler drains vmcnt before barrier

        #pragma unroll
        for (int c = 0; c < 4; ++c) {
            int gsel = ((c * 4 + (lane >> 4)) ^ (lane & 7)) << 4;
            bf16x8 a0 = *(const bf16x8*)(sA + (wy * 32 + (lane & 15)) * 256 + gsel);
            bf16x8 a1 = *(const bf16x8*)(sA + (wy * 32 + 16 + (lane & 15)) * 256 + gsel);
            #pragma unroll
            for (int nj = 0; nj < 4; ++nj) {
                bf16x8 bb = *(const bf16x8*)(sW + (wx * 64 + nj * 16 + (lane & 15)) * 256 + gsel);
                acc[0][nj] = __builtin_amdgcn_mfma_f32_16x16x32_bf16(a0, bb, acc[0][nj], 0, 0, 0);
                acc[1][nj] = __builtin_amdgcn_mfma_f32_16x16x32_bf16(a1, bb, acc[1][nj], 0, 0, 0);
            }
        }
    }

    const float inv7 = 1.0f / (float)NT;
    #pragma unroll
    for (int mi = 0; mi < 2; ++mi) {
        #pragma unroll
        for (int v = 0; v < 4; ++v) {
            int n = n0 + wy * 32 + mi * 16 + (lane >> 4) * 4 + v;
            if (n >= NN) continue;
            float add[4] = {0.f, 0.f, 0.f, 0.f};
            for (int t = 0; t < tc; ++t) {
                if (cnt[t * NN + n] > 0) {
                    #pragma unroll
                    for (int nj = 0; nj < 4; ++nj)
                        add[nj] += bias[(size_t)(t0 + t) * DD + wx * 64 + nj * 16 + (lane & 15)];
                }
            }
            #pragma unroll
            for (int nj = 0; nj < 4; ++nj) {
                float val = inv7 * (acc[mi][nj][v] + add[nj]);
                float* op = out + (size_t)n * DD + wx * 64 + nj * 16 + (lane & 15);
                if (accum) *op += val; else *op = val;
            }
        }
    }
}

// ---------------------------------------------------------------- launch ----
extern "C" void kernel_launch(void* const* d_in, const int* in_sizes, int n_in,
                              void* d_out, int out_size, void* d_ws, size_t ws_size,
                              hipStream_t stream) {
    const float* x  = (const float*)d_in[0];
    const int*   ei = (const int*)d_in[1];
    const float* W  = (const float*)d_in[2];
    const float* b  = (const float*)d_in[3];
    float* out = (float*)d_out;
    char* ws = (char*)d_ws;

    const size_t WTB_BYTES = (size_t)NT * 128 * 256;                      // 224 KB
    const size_t perType = (size_t)NTILE * 16384                          // aggb 25.6MB
                         + (size_t)NN * CAP * 4                           // eidx 12.8MB
                         + (size_t)NN * 4;                                // cnt   0.4MB
    int tcmax = (ws_size > WTB_BYTES) ? (int)((ws_size - WTB_BYTES) / perType) : 1;
    if (tcmax < 1) tcmax = 1;
    if (tcmax > NT) tcmax = NT;

    char* aggb = ws;
    int*  eidx = (int*)(ws + (size_t)tcmax * NTILE * 16384);
    int*  cnti = (int*)((char*)eidx + (size_t)tcmax * NN * CAP * 4);
    char* WTb  = (char*)cnti + (size_t)tcmax * NN * 4;

    wconv_k<<<(NT * 128 + 3) / 4, 256, 0, stream>>>(W, WTb);

    int accum = (tcmax < NT) ? 1 : 0;
    if (accum) hipMemsetAsync(out, 0, (size_t)NN * DD * sizeof(float), stream);

    for (int t0 = 0; t0 < NT; t0 += tcmax) {
        int tc = (NT - t0 < tcmax) ? (NT - t0) : tcmax;
        hipMemsetAsync(cnti, 0, (size_t)tc * NN * 4, stream);
        int nedge = tc * NE;
        fill_k<<<(nedge + 255) / 256, 256, 0, stream>>>(
            ei + (size_t)t0 * 2 * NE, cnti, eidx, nedge);
        int npair = tc * NN;
        agg_k<<<(npair + 3) / 4, 256, 0, stream>>>(x, cnti, eidx, aggb, npair);
        gemm_k<<<NTILE, 256, 0, stream>>>(aggb, WTb, cnti, b, out, tc, t0, accum);
    }
}

// Round 3
// 525.551 us; speedup vs baseline: 6.6684x; 1.0327x over previous
//
#include <hip/hip_runtime.h>

// SwitchGNN restructured:
//  out = (1/7) * sum_t [ (segsum_t(x[src]) / max(cnt,1)) @ W_t + 1{cnt>0} b_t ]
// P0 convx_k: x -> bf16 rows (256B) once; halves gather payload in agg_k
// P1 fill_k : bucket edges by (t,dst)   (1 int atomic/edge, cap 32)
// P2 agg_k  : gather-sum bf16 x rows per (t,n) in fp32, scale 1/cnt,
//             emit bf16 pre-swizzled for the GEMM's ds_read_b128
// P3 wconv_k: W -> bf16, transposed [t][f][k], same XOR swizzle (once)
// P4 gemm_k : 64-row blocks, LDS-staged A/W via global_load_lds(16B),
//             mfma_f32_16x16x32_bf16, bias+mean epilogue.

constexpr int NN = 100000;
constexpr int NT = 7;
constexpr int NE = 250000;
constexpr int DD = 128;
constexpr int CAP = 32;                 // bucket capacity (P(ovfl)~1e-22 @ lambda=2.5)
constexpr int NTILE = (NN + 63) / 64;   // 1563 GEMM row-tiles

typedef short bf16x8 __attribute__((ext_vector_type(8)));
typedef float f32x4 __attribute__((ext_vector_type(4)));

__device__ __forceinline__ unsigned pack_bf16x2(float lo, float hi) {
    unsigned a = __float_as_uint(lo), b = __float_as_uint(hi);
    unsigned al = (a + 0x7FFFu + ((a >> 16) & 1u)) >> 16;          // RNE
    unsigned bh = (b + 0x7FFFu + ((b >> 16) & 1u)) & 0xFFFF0000u;
    return al | bh;
}

// ---------------------------------------------------------------- conv x ----
// 8 floats -> 4 packed dwords per thread. 12.8M elements total.
__global__ __launch_bounds__(256) void convx_k(
    const float* __restrict__ x, uint4* __restrict__ xb)
{
    int id = blockIdx.x * 256 + threadIdx.x;
    const float4* src = (const float4*)x;
    float4 v0 = src[(size_t)id * 2];
    float4 v1 = src[(size_t)id * 2 + 1];
    uint4 o;
    o.x = pack_bf16x2(v0.x, v0.y);
    o.y = pack_bf16x2(v0.z, v0.w);
    o.z = pack_bf16x2(v1.x, v1.y);
    o.w = pack_bf16x2(v1.z, v1.w);
    xb[id] = o;
}

// ------------------------------------------------------------------ fill ----
__global__ __launch_bounds__(256) void fill_k(
    const int* __restrict__ ei,     // [tc][2][NE] (chunk base)
    int* __restrict__ cnt,          // [tc*NN], zeroed
    int* __restrict__ eidx,         // [tc*NN][CAP]
    int nedge)
{
    int id = blockIdx.x * 256 + threadIdx.x;
    if (id >= nedge) return;
    int t = id / NE, e = id - t * NE;
    const int* p = ei + (size_t)t * 2 * NE;
    int src = p[e], dst = p[NE + e];
    int slot = t * NN + dst;
    int pos = atomicAdd(cnt + slot, 1);
    if (pos < CAP) eidx[(size_t)slot * CAP + pos] = src;
}

// ------------------------------------------------------------- aggregate ----
// one wave per (t,n); lane holds features 2*lane, 2*lane+1 (one dword of bf16)
__global__ __launch_bounds__(256) void agg_k(
    const char* __restrict__ xb,    // [NN][256B] bf16 rows
    const int* __restrict__ cnt,
    const int* __restrict__ eidx,
    char* __restrict__ aggb,        // [tc][NTILE][64 rows][256B], swizzled
    int npair)
{
    int wid = (blockIdx.x * 256 + threadIdx.x) >> 6;
    int lane = threadIdx.x & 63;
    if (wid >= npair) return;
    int t = wid / NN, n = wid - t * NN;
    int c = cnt[wid];
    int cc = c < CAP ? c : CAP;
    const int* bkt = eidx + (size_t)wid * CAP;
    int my = (lane < cc) ? bkt[lane] : 0;   // vectorized index prefetch

    float a0 = 0.f, a1 = 0.f;
    int e = 0;
    for (; e + 4 <= cc; e += 4) {           // 4 independent gathers in flight
        int s0 = __shfl(my, e), s1 = __shfl(my, e + 1);
        int s2 = __shfl(my, e + 2), s3 = __shfl(my, e + 3);
        unsigned v0 = *(const unsigned*)(xb + (size_t)s0 * 256 + lane * 4);
        unsigned v1 = *(const unsigned*)(xb + (size_t)s1 * 256 + lane * 4);
        unsigned v2 = *(const unsigned*)(xb + (size_t)s2 * 256 + lane * 4);
        unsigned v3 = *(const unsigned*)(xb + (size_t)s3 * 256 + lane * 4);
        a0 += __uint_as_float(v0 << 16) + __uint_as_float(v1 << 16)
            + __uint_as_float(v2 << 16) + __uint_as_float(v3 << 16);
        a1 += __uint_as_float(v0 & 0xFFFF0000u) + __uint_as_float(v1 & 0xFFFF0000u)
            + __uint_as_float(v2 & 0xFFFF0000u) + __uint_as_float(v3 & 0xFFFF0000u);
    }
    for (; e < cc; ++e) {
        int s = __shfl(my, e);
        unsigned v = *(const unsigned*)(xb + (size_t)s * 256 + lane * 4);
        a0 += __uint_as_float(v << 16);
        a1 += __uint_as_float(v & 0xFFFF0000u);
    }
    float s = 1.0f / fmaxf((float)c, 1.0f);  // fold mean-scale pre-GEMM (linear)
    int g = n >> 6, r = n & 63;
    int gran = (lane >> 2) ^ (r & 7);        // XOR swizzle: conflict-free ds_read_b128
    *(unsigned*)(aggb + ((size_t)t * NTILE + g) * 16384 + r * 256 + gran * 16 + (lane & 3) * 4)
        = pack_bf16x2(a0 * s, a1 * s);
}

// ---------------------------------------------------------------- W conv ----
// WTb[t][f][k] bf16, row=256B, granule ^= f&7. One wave per (t,f).
__global__ __launch_bounds__(256) void wconv_k(
    const float* __restrict__ W, char* __restrict__ WTb)
{
    int wid = (blockIdx.x * 256 + threadIdx.x) >> 6;
    int lane = threadIdx.x & 63;
    int t = wid >> 7, f = wid & 127;
    if (t >= NT) return;
    const float* Wt = W + (size_t)t * DD * DD;
    float w0 = Wt[(size_t)(2 * lane) * DD + f];
    float w1 = Wt[(size_t)(2 * lane + 1) * DD + f];
    int gran = (lane >> 2) ^ (f & 7);
    *(unsigned*)(WTb + (size_t)t * 32768 + f * 256 + gran * 16 + (lane & 3) * 4)
        = pack_bf16x2(w0, w1);
}

// ------------------------------------------------------------------ gemm ----
// 4 waves: wave(wy,wx) computes rows wy*32..+31, cols wx*64..+63.
__global__ __launch_bounds__(256) void gemm_k(
    const char* __restrict__ aggb, const char* __restrict__ WTb,
    const int* __restrict__ cnt, const float* __restrict__ bias,
    float* __restrict__ out, int tc, int t0, int accum)
{
    __shared__ char sA[64 * 256];    // 16 KB
    __shared__ char sW[128 * 256];   // 32 KB
    int tid = threadIdx.x;
    int w = tid >> 6, lane = tid & 63;
    int wy = w >> 1, wx = w & 1;
    int n0 = blockIdx.x * 64;

    f32x4 acc[2][4];
    #pragma unroll
    for (int i = 0; i < 2; ++i)
        #pragma unroll
        for (int j = 0; j < 4; ++j) acc[i][j] = (f32x4)0.0f;

    for (int t = 0; t < tc; ++t) {
        __syncthreads();   // prev iter's readers done before restage
        const char* asrc = aggb + ((size_t)t * NTILE + blockIdx.x) * 16384;
        #pragma unroll
        for (int i = 0; i < 4; ++i) {
            int ch = w * 4 + i;
            __builtin_amdgcn_global_load_lds(
                (const __attribute__((address_space(1))) void*)(asrc + ch * 1024 + lane * 16),
                (__attribute__((address_space(3))) void*)(sA + ch * 1024), 16, 0, 0);
        }
        const char* wsrc = WTb + (size_t)(t0 + t) * 32768;
        #pragma unroll
        for (int i = 0; i < 8; ++i) {
            int ch = w * 8 + i;
            __builtin_amdgcn_global_load_lds(
                (const __attribute__((address_space(1))) void*)(wsrc + ch * 1024 + lane * 16),
                (__attribute__((address_space(3))) void*)(sW + ch * 1024), 16, 0, 0);
        }
        __syncthreads();   // compiler drains vmcnt before barrier

        #pragma unroll
        for (int c = 0; c < 4; ++c) {
            int gsel = ((c * 4 + (lane >> 4)) ^ (lane & 7)) << 4;
            bf16x8 a0 = *(const bf16x8*)(sA + (wy * 32 + (lane & 15)) * 256 + gsel);
            bf16x8 a1 = *(const bf16x8*)(sA + (wy * 32 + 16 + (lane & 15)) * 256 + gsel);
            #pragma unroll
            for (int nj = 0; nj < 4; ++nj) {
                bf16x8 bb = *(const bf16x8*)(sW + (wx * 64 + nj * 16 + (lane & 15)) * 256 + gsel);
                acc[0][nj] = __builtin_amdgcn_mfma_f32_16x16x32_bf16(a0, bb, acc[0][nj], 0, 0, 0);
                acc[1][nj] = __builtin_amdgcn_mfma_f32_16x16x32_bf16(a1, bb, acc[1][nj], 0, 0, 0);
            }
        }
    }

    const float inv7 = 1.0f / (float)NT;
    #pragma unroll
    for (int mi = 0; mi < 2; ++mi) {
        #pragma unroll
        for (int v = 0; v < 4; ++v) {
            int n = n0 + wy * 32 + mi * 16 + (lane >> 4) * 4 + v;
            if (n >= NN) continue;
            float add[4] = {0.f, 0.f, 0.f, 0.f};
            for (int t = 0; t < tc; ++t) {
                if (cnt[t * NN + n] > 0) {
                    #pragma unroll
                    for (int nj = 0; nj < 4; ++nj)
                        add[nj] += bias[(size_t)(t0 + t) * DD + wx * 64 + nj * 16 + (lane & 15)];
                }
            }
            #pragma unroll
            for (int nj = 0; nj < 4; ++nj) {
                float val = inv7 * (acc[mi][nj][v] + add[nj]);
                float* op = out + (size_t)n * DD + wx * 64 + nj * 16 + (lane & 15);
                if (accum) *op += val; else *op = val;
            }
        }
    }
}

// ---------------------------------------------------------------- launch ----
extern "C" void kernel_launch(void* const* d_in, const int* in_sizes, int n_in,
                              void* d_out, int out_size, void* d_ws, size_t ws_size,
                              hipStream_t stream) {
    const float* x  = (const float*)d_in[0];
    const int*   ei = (const int*)d_in[1];
    const float* W  = (const float*)d_in[2];
    const float* b  = (const float*)d_in[3];
    float* out = (float*)d_out;
    char* ws = (char*)d_ws;

    const size_t WTB_BYTES = (size_t)NT * 128 * 256;                      // 224 KB
    const size_t XB_BYTES  = (size_t)NN * 256;                            // 25.6 MB
    const size_t perType = (size_t)NTILE * 16384                          // aggb 25.6MB
                         + (size_t)NN * CAP * 4                           // eidx 12.8MB
                         + (size_t)NN * 4;                                // cnt   0.4MB
    size_t fixed = WTB_BYTES + XB_BYTES;
    int tcmax = (ws_size > fixed) ? (int)((ws_size - fixed) / perType) : 1;
    if (tcmax < 1) tcmax = 1;
    if (tcmax > NT) tcmax = NT;

    char* aggb = ws;
    int*  eidx = (int*)(ws + (size_t)tcmax * NTILE * 16384);
    int*  cnti = (int*)((char*)eidx + (size_t)tcmax * NN * CAP * 4);
    char* WTb  = (char*)cnti + (size_t)tcmax * NN * 4;
    char* xb   = WTb + WTB_BYTES;

    convx_k<<<(NN * DD / 8 + 255) / 256, 256, 0, stream>>>(x, (uint4*)xb);
    wconv_k<<<(NT * 128 + 3) / 4, 256, 0, stream>>>(W, WTb);

    int accum = (tcmax < NT) ? 1 : 0;
    if (accum) hipMemsetAsync(out, 0, (size_t)NN * DD * sizeof(float), stream);

    for (int t0 = 0; t0 < NT; t0 += tcmax) {
        int tc = (NT - t0 < tcmax) ? (NT - t0) : tcmax;
        hipMemsetAsync(cnti, 0, (size_t)tc * NN * 4, stream);
        int nedge = tc * NE;
        fill_k<<<(nedge + 255) / 256, 256, 0, stream>>>(
            ei + (size_t)t0 * 2 * NE, cnti, eidx, nedge);
        int npair = tc * NN;
        agg_k<<<(npair + 3) / 4, 256, 0, stream>>>(xb, cnti, eidx, aggb, npair);
        gemm_k<<<NTILE, 256, 0, stream>>>(aggb, WTb, cnti, b, out, tc, t0, accum);
    }
}